// Round 4
// baseline (600.382 us; speedup 1.0000x reference)
//
#include <hip/hip_runtime.h>
#include <stdint.h>

typedef unsigned short u16;
typedef short bf16x8 __attribute__((ext_vector_type(8)));
typedef float f32x4 __attribute__((ext_vector_type(4)));

__device__ __forceinline__ float b2f(u16 u){
  unsigned int i = ((unsigned int)u) << 16;
  return __builtin_bit_cast(float, i);
}
__device__ __forceinline__ u16 f2b(float f){
  unsigned int i = __builtin_bit_cast(unsigned int, f);
  i += 0x7FFFu + ((i >> 16) & 1u);   // round-nearest-even
  return (u16)(i >> 16);
}

__device__ __forceinline__ void async16(const void* g, void* l){
  __builtin_amdgcn_global_load_lds((__attribute__((address_space(1))) void*)(void*)g,
                                   (__attribute__((address_space(3))) void*)l, 16, 0, 0);
}

// local dtype probe: 256 samples of q_w, identical in every block (deterministic).
// fp32: low-half u16s have (bits14..7)=mantissa-mid -> ~45% >=140 -> cnt~58 of 256.
// bf16: (bits14..7)=exp ~122 -> cnt~0.  Threshold 20.
__device__ __forceinline__ int local_isf32(const u16* __restrict__ qw){
  int c = 0;
#pragma unroll
  for (int j = 0; j < 32; ++j){
    bf16x8 v = *(const bf16x8*)(qw + j*8);
#pragma unroll
    for (int k = 0; k < 8; ++k) c += ((((u16)v[k] >> 7) & 0xFF) >= 140);
  }
  return c > 20;
}

// ---------------- fused prep: cvt-x | cvt-4-weights | cvt-bias ----------------
// grid 15003 x 256: [0,13848) x-chunks, [13848,15000) weight-chunks, [15000,15003) bias
__global__ __launch_bounds__(256) void prep_kernel(
    const void* __restrict__ x,
    const void* __restrict__ s0, const void* __restrict__ s1,
    const void* __restrict__ s2, const void* __restrict__ s3,
    u16* __restrict__ xb, u16* __restrict__ wb, float* __restrict__ biasf,
    const void* __restrict__ pb)
{
  const int bid = blockIdx.x, tid = threadIdx.x;
  const int isf32 = local_isf32((const u16*)s0);

  if (bid < 13848){
    const int i = bid * 2048 + tid * 8;
    if (isf32){
      f32x4 a = *(const f32x4*)((const float*)x + i);
      f32x4 b = *(const f32x4*)((const float*)x + i + 4);
      bf16x8 v;
#pragma unroll
      for (int j = 0; j < 4; ++j){ v[j] = (short)f2b(a[j]); v[4+j] = (short)f2b(b[j]); }
      *(bf16x8*)(xb + i) = v;
    } else {
      *(bf16x8*)(xb + i) = *(const bf16x8*)((const u16*)x + i);
    }
  } else if (bid < 15000){
    const int b = bid - 13848;                // 0..1151, 288 per weight
    const int wsel = b / 288;
    const int i = (b - wsel*288) * 2048 + tid * 8;
    const void* src = (wsel == 0) ? s0 : (wsel == 1) ? s1 : (wsel == 2) ? s2 : s3;
    u16* d = wb + (size_t)wsel * 589824 + i;
    if (isf32){
      f32x4 a = *(const f32x4*)((const float*)src + i);
      f32x4 c = *(const f32x4*)((const float*)src + i + 4);
      bf16x8 v;
#pragma unroll
      for (int j = 0; j < 4; ++j){ v[j] = (short)f2b(a[j]); v[4+j] = (short)f2b(c[j]); }
      *(bf16x8*)d = v;
    } else {
      *(bf16x8*)d = *(const bf16x8*)((const u16*)src + i);
    }
  } else {
    const int i = (bid - 15000) * 256 + tid;
    if (i < 768) biasf[i] = isf32 ? ((const float*)pb)[i] : b2f(((const u16*)pb)[i]);
  }
}

// ---------------- top-k: rank-by-counting, tie-break lower index ----------------
__global__ __launch_bounds__(576) void topk_kernel(const void* __restrict__ aa,
                                                   int* __restrict__ qrows,
                                                   const u16* __restrict__ qw){
  const int b = blockIdx.x;
  const int isf32 = local_isf32(qw);
  __shared__ float vals[576];
  const int i = threadIdx.x;           // 0..575
  const size_t off = (size_t)b*332929 + 1 + i;   // 577*577 = 332929
  vals[i] = isf32 ? ((const float*)aa)[off] : b2f(((const u16*)aa)[off]);
  __syncthreads();
  const float vi = vals[i];
  int rank = 0;
  for (int j = 0; j < 576; ++j){
    float vj = vals[j];
    rank += (int)((vj > vi) || (vj == vi && j < i));
  }
  if (rank < 57) qrows[b*58 + 1 + rank] = b*577 + i + 1;
  if (i == 0)    qrows[b*58] = b*577;
}

// ---------------- fused GEMM ----------------
// mode 0: 1D grid 5376. bid<5202: bijective XCD chunk (5202=8*650+2, m204 formula)
//         then (bx=wg%18, by=wg/18), W rows 768+nBase (k|v|p); epilogue by n-range:
//         K bf16 | Vt transposed | out fp32+bias.
//         bid>=5202: lq part UNswizzled (tail spreads across all XCDs), gathered A.
// mode 1: 2D grid (6,29): final scatter proj.
// Core: 3-buffer ring, ONE barrier per K-step (24 vs 48):
//   phase t: vmcnt(4); s_barrier; STAGE(buf[(t+2)%3], t+2); ds_read buf[t%3]; MFMA
// Safety: per-wave vmcnt(4) BEFORE the barrier -> tile t fully landed (all waves)
// after the barrier; stage target never equals read target or in-flight buffer;
// a wave's buf[t] reads complete (MFMA data-dep) before it reaches barrier t+1,
// so restaging buf[t] at phase t+1 cannot overwrite pending reads.
// LDS 48KB -> 3 blocks/CU. Swizzle: chunk ^= (row>>1)&3 both-sides (rule #21).
__global__ __launch_bounds__(256, 3) void gemm_bt(
    const u16* __restrict__ A, const u16* __restrict__ W,
    u16* __restrict__ Ck, u16* __restrict__ Cvt, float* __restrict__ Cout,
    u16* __restrict__ Clq,
    const int* __restrict__ qrows, const float* __restrict__ bias, int mode)
{
  __shared__ __align__(16) u16 As0[4096], As1[4096], As2[4096];
  __shared__ __align__(16) u16 Bs0[4096], Bs1[4096], Bs2[4096];
  const int tid = threadIdx.x;
  const int w = tid >> 6, l = tid & 63;

  int bx, by; bool lqp = false;
  if (mode == 0){
    const int bid = blockIdx.x;
    if (bid < 5202){
      const int x = bid & 7, o = bid >> 3;     // 5202 = 8*650+2: xcd 0,1 get 651
      const int wg = (x < 2 ? x*651 : 2*651 + (x-2)*650) + o;
      bx = wg % 18; by = wg / 18;
    } else { const int t = bid - 5202; bx = t % 6; by = t / 6; lqp = true; }
  } else { bx = blockIdx.x; by = blockIdx.y; }

  const int mBase = by * 128;
  const int nBase = bx * 128;
  const int Meff  = (mode == 0 && !lqp) ? 36928 : 3712;

  const int r0 = tid >> 2;
  // source chunk pre-swizzled so LDS(r,c) holds global chunk c^((r>>1)&3)
  const int kc = (((tid & 3) ^ ((r0 >> 1) & 3)) * 8);
  int arow0 = mBase + r0;       if (arow0 > Meff-1) arow0 = Meff-1;
  int arow1 = mBase + 64 + r0;  if (arow1 > Meff-1) arow1 = Meff-1;
  if (mode == 0 && lqp){ arow0 = qrows[arow0]; arow1 = qrows[arow1]; }
  const int wrowBase = (mode == 0 && !lqp) ? (768 + nBase) : nBase;
  const u16* ag0 = A + (size_t)arow0 * 768 + kc;
  const u16* ag1 = A + (size_t)arow1 * 768 + kc;
  const u16* bg0 = W + (size_t)(wrowBase + r0) * 768 + kc;
  const u16* bg1 = W + (size_t)(wrowBase + 64 + r0) * 768 + kc;
  const int toff0 = tid * 8, toff1 = (256 + tid) * 8;

  f32x4 acc[4][4] = {};
  const int wm = (w >> 1) * 64, wn = (w & 1) * 64;
  const int lm = l & 15;
  // swizzled read chunk: global chunk l>>4 of row with (row>>1)&3 == (l>>1)&3
  const int lkx = (((l >> 4) ^ ((l >> 1) & 3)) * 8);

#define STAGE(Ab, Bb, koff) do { \
    async16(ag0 + (koff), &Ab[toff0]); \
    async16(ag1 + (koff), &Ab[toff1]); \
    async16(bg0 + (koff), &Bb[toff0]); \
    async16(bg1 + (koff), &Bb[toff1]); } while(0)

#define COMPUTE(Ab, Bb) { \
    bf16x8 af[4], bfr[4]; \
    _Pragma("unroll") \
    for (int i = 0; i < 4; ++i) af[i]  = *(const bf16x8*)&Ab[(wm + i*16 + lm)*32 + lkx]; \
    _Pragma("unroll") \
    for (int j = 0; j < 4; ++j) bfr[j] = *(const bf16x8*)&Bb[(wn + j*16 + lm)*32 + lkx]; \
    __builtin_amdgcn_s_setprio(1); \
    _Pragma("unroll") \
    for (int i = 0; i < 4; ++i) \
      _Pragma("unroll") \
      for (int j = 0; j < 4; ++j) \
        acc[i][j] = __builtin_amdgcn_mfma_f32_16x16x32_bf16(af[i], bfr[j], acc[i][j], 0, 0, 0); \
    __builtin_amdgcn_s_setprio(0); }

#define VMW4 asm volatile("s_waitcnt vmcnt(4)" ::: "memory")
#define VMW0 asm volatile("s_waitcnt vmcnt(0)" ::: "memory")
#define BAR  __builtin_amdgcn_s_barrier()

  // prologue: tiles 0,1 in flight (8 outstanding per wave)
  STAGE(As0, Bs0, 0);
  STAGE(As1, Bs1, 32);
  // phases t=0..20 (+ t=21 with last stage): stage t+2, read buf t%3
#pragma unroll
  for (int u = 0; u < 7; ++u){
    VMW4; BAR; STAGE(As2, Bs2, u*96 + 64);  COMPUTE(As0, Bs0);   // t=3u
    VMW4; BAR; STAGE(As0, Bs0, u*96 + 96);  COMPUTE(As1, Bs1);   // t=3u+1
    VMW4; BAR; STAGE(As1, Bs1, u*96 + 128); COMPUTE(As2, Bs2);   // t=3u+2
  }
  VMW4; BAR; STAGE(As2, Bs2, 736); COMPUTE(As0, Bs0);            // t=21, stage t=23
  VMW4; BAR;                       COMPUTE(As1, Bs1);            // t=22
  VMW0; BAR;                       COMPUTE(As2, Bs2);            // t=23 (drain)

#undef STAGE
#undef COMPUTE
#undef VMW4
#undef VMW0
#undef BAR

  // epilogue: C layout col=lane&15, row=(lane>>4)*4+reg
  if (mode == 1){
#pragma unroll
    for (int i = 0; i < 4; ++i){
#pragma unroll
      for (int r = 0; r < 4; ++r){
        int m = mBase + wm + i*16 + ((l >> 4) << 2) + r;
        if (m < 3712){
          size_t base = (size_t)qrows[m] * 768;
#pragma unroll
          for (int j = 0; j < 4; ++j){
            int n = nBase + wn + j*16 + lm;
            Cout[base + n] = acc[i][j][r] + bias[n];
          }
        }
      }
    }
    return;
  }
  if (lqp){
#pragma unroll
    for (int i = 0; i < 4; ++i){
#pragma unroll
      for (int r = 0; r < 4; ++r){
        int m = mBase + wm + i*16 + ((l >> 4) << 2) + r;
#pragma unroll
        for (int j = 0; j < 4; ++j){
          int n = nBase + wn + j*16 + lm;
          Clq[(size_t)m*768 + n] = f2b(acc[i][j][r]);
        }
      }
    }
  } else if (nBase < 768){
#pragma unroll
    for (int i = 0; i < 4; ++i){
#pragma unroll
      for (int r = 0; r < 4; ++r){
        int m = mBase + wm + i*16 + ((l >> 4) << 2) + r;
        if (m < 36928){
#pragma unroll
          for (int j = 0; j < 4; ++j){
            int n = nBase + wn + j*16 + lm;
            Ck[(size_t)m*768 + n] = f2b(acc[i][j][r]);
          }
        }
      }
    }
  } else if (nBase < 1536){
    // Vt transposed per head: [(b*12+h)*64 + d][608]
#pragma unroll
    for (int i = 0; i < 4; ++i){
#pragma unroll
      for (int r = 0; r < 4; ++r){
        int m = mBase + wm + i*16 + ((l >> 4) << 2) + r;
        if (m < 36928){
          int bb = m / 577;
          int nn = m - bb*577;
#pragma unroll
          for (int j = 0; j < 4; ++j){
            int nf = nBase - 768 + wn + j*16 + lm;     // feature = h*64+d
            Cvt[((size_t)(bb*12 + (nf >> 6))*64 + (nf & 63))*608 + nn] = f2b(acc[i][j][r]);
          }
        }
      }
    }
  } else {
#pragma unroll
    for (int i = 0; i < 4; ++i){
#pragma unroll
      for (int r = 0; r < 4; ++r){
        int m = mBase + wm + i*16 + ((l >> 4) << 2) + r;
        if (m < 36928){
          size_t base = (size_t)m * 768;
#pragma unroll
          for (int j = 0; j < 4; ++j){
            int nf = nBase - 1536 + wn + j*16 + lm;
            Cout[base + nf] = acc[i][j][r] + bias[nf];
          }
        }
      }
    }
  }
}

// ---------------- attention: 512 threads (8 waves), 1D grid 3072 XCD-chunked ----
// QK^T strided over 8 waves (<=5 serial iters/wave, was 9+); PV split: waves
// (w, w+4) each do 9 of 18 k-steps for d-tile w&3, partials combined through S
// (dead after PV reads). LDS 39.1KB -> 4 blocks/CU, up to 32 waves/CU of TLP.
#define SLD 580   // score LDS row stride in floats (577 data + 3 pad)
__global__ __launch_bounds__(512) void attn_kernel(
    const u16* __restrict__ lq, const u16* __restrict__ K,
    const u16* __restrict__ Vt, u16* __restrict__ lout)
{
  const int bid = blockIdx.x;
  const int wg = (bid & 7) * 384 + (bid >> 3);   // 3072 = 8*384 exact
  const int mt = wg & 3;
  const int hb = wg >> 2;
  const int h = hb % 12, b = hb / 12;

  __shared__ __align__(16) u16 qs[16*64];        // reused as red/inv after scores
  __shared__ __align__(16) float S[16*SLD];
  float* red  = (float*)qs;                      // 16*17 floats
  float* invp = red + 16*17;                     // +16 floats (<=2048B total)
  const int tid = threadIdx.x, w = tid >> 6, l = tid & 63;
  const int lm = l & 15, lk = (l >> 4) * 8;

  for (int idx = tid; idx < 1024; idx += 512){
    int r = idx >> 6, c = idx & 63;
    int gm = mt*16 + r;
    qs[idx] = (gm < 58) ? lq[((size_t)b*58 + gm)*768 + h*64 + c] : (u16)0;
  }
  __syncthreads();
  bf16x8 aq0 = *(const bf16x8*)&qs[lm*64 + lk];
  bf16x8 aq1 = *(const bf16x8*)&qs[lm*64 + 32 + lk];

  // scores: S[m][n] = (Q·K^T)*0.125 for n<577; 8 waves stride the 37 n-tiles
  const u16* Kb = K + (size_t)b*577*768 + h*64;
  for (int t = w; t < 37; t += 8){
    int n = t*16 + lm; if (n > 576) n = 576;
    const u16* kp = Kb + (size_t)n*768;
    bf16x8 b0 = *(const bf16x8*)&kp[lk];
    bf16x8 b1 = *(const bf16x8*)&kp[32 + lk];
    f32x4 c = {};
    c = __builtin_amdgcn_mfma_f32_16x16x32_bf16(aq0, b0, c, 0, 0, 0);
    c = __builtin_amdgcn_mfma_f32_16x16x32_bf16(aq1, b1, c, 0, 0, 0);
    const int n0 = t*16;
    if (n0 + lm < 577){
#pragma unroll
      for (int r = 0; r < 4; ++r)
        S[(((l >> 4) << 2) + r)*SLD + n0 + lm] = c[r] * 0.125f;
    }
  }
  __syncthreads();

  // softmax (threads 0..255): max pass + exp/sum pass; inv applied at the end
  const int row = tid >> 4, g = tid & 15;
  float sum = 0.f;
  if (tid < 256){
    float mx = -1e30f;
    for (int n = g; n < 577; n += 16) mx = fmaxf(mx, S[row*SLD + n]);
    red[row*17 + g] = mx;
  }
  __syncthreads();
  if (tid < 256){
    float m2 = red[row*17];
#pragma unroll
    for (int i = 1; i < 16; ++i) m2 = fmaxf(m2, red[row*17 + i]);
    for (int n = g; n < 577; n += 16){
      float e = __expf(S[row*SLD + n] - m2);
      S[row*SLD + n] = e;
      sum += e;
    }
  }
  __syncthreads();
  if (tid < 256) red[row*17 + g] = sum;
  __syncthreads();
  if (tid < 256 && g == 0){
    float s2 = 0.f;
#pragma unroll
    for (int i = 0; i < 16; ++i) s2 += red[row*17 + i];
    invp[row] = 1.f / s2;
  }
  __syncthreads();

  // O = (P_unnorm · V) * inv; d-tile = w&3; k-half = w>>2 (9 of 18 k-steps each)
  const u16* Vrow = Vt + (((size_t)(b*12 + h) * 64) + (w & 3)*16 + lm) * 608;
  const int ksbeg = (w >> 2) * 9;
  f32x4 oc = {};
  for (int i = 0; i < 9; ++i){
    const int kb = (ksbeg + i)*32 + lk;
    f32x4 p0 = *(const f32x4*)&S[lm*SLD + kb];
    f32x4 p1 = *(const f32x4*)&S[lm*SLD + kb + 4];
    bf16x8 af;
#pragma unroll
    for (int j = 0; j < 4; ++j){ af[j] = (short)f2b(p0[j]); af[4+j] = (short)f2b(p1[j]); }
    bf16x8 bv = *(const bf16x8*)&Vrow[kb];
    oc = __builtin_amdgcn_mfma_f32_16x16x32_bf16(af, bv, oc, 0, 0, 0);
  }
  // tail n=576 (added once, by the low-half waves)
  if (w < 4){
    float vt576 = b2f(Vrow[576]);
#pragma unroll
    for (int r = 0; r < 4; ++r)
      oc[r] += S[(((l >> 4) << 2) + r)*SLD + 576] * vt576;
  }
  __syncthreads();                      // all PV reads of S done
  if (w >= 4){
    float* scr = (float*)S;             // S dead: reuse first 1024 floats
#pragma unroll
    for (int r = 0; r < 4; ++r) scr[(w - 4)*256 + l*4 + r] = oc[r];
  }
  __syncthreads();
  if (w < 4){
    const float* scr = (const float*)S;
#pragma unroll
    for (int r = 0; r < 4; ++r){
      int sr = (((l >> 4) << 2) + r);
      float v = (oc[r] + scr[w*256 + l*4 + r]) * invp[sr];
      int ml = mt*16 + sr;
      if (ml < 58)
        lout[((size_t)b*58 + ml)*768 + h*64 + (w & 3)*16 + lm] = f2b(v);
    }
  }
}

// ---------------- launch ----------------
extern "C" void kernel_launch(void* const* d_in, const int* in_sizes, int n_in,
                              void* d_out, int out_size, void* d_ws, size_t ws_size,
                              hipStream_t stream)
{
  const void* x    = d_in[0];
  const void* aacc = d_in[1];
  const void* q_w  = d_in[2];
  const void* k_w  = d_in[3];
  const void* v_w  = d_in[4];
  const void* p_w  = d_in[5];
  const void* p_b  = d_in[6];

  const int M  = 36928;   // 64*577
  const int Ms = 3712;    // 64*58
  const int XE = M * 768;       // 28,360,704
  const int WE = 768 * 768;     // 589,824

  u16* Kbuf = (u16*)d_ws;                              // 36928*768
  u16* Vt   = Kbuf + (size_t)M * 768;                  // 768*64*608 (b*12+h, d, n)
  u16* lq   = Vt + (size_t)768 * 64 * 608;             // 3712*768
  u16* lout = lq + (size_t)Ms * 768;                   // 3712*768
  u16* xb   = lout + (size_t)Ms * 768;                 // 36928*768 bf16 x
  u16* qwb  = xb + (size_t)XE;                         // 4 weights bf16 [q;k;v;p]
  u16* pwb  = qwb + (size_t)3 * WE;
  float* biasf = (float*)(qwb + (size_t)4 * WE);       // 768 fp32
  int* qrows = (int*)(biasf + 768);                    // 3712 ints

  prep_kernel<<<15003, 256, 0, stream>>>(x, q_w, k_w, v_w, p_w, xb, qwb, biasf, p_b);
  topk_kernel<<<64, 576, 0, stream>>>(aacc, qrows, (const u16*)q_w);

  // fused: K | Vt | proj-out (18 n-tiles x 289 m-tiles) + gathered lq (6 x 29)
  gemm_bt<<<5376, 256, 0, stream>>>(xb, qwb, Kbuf, Vt, (float*)d_out, lq,
                                    qrows, biasf, 0);
  // attention -> local_out
  attn_kernel<<<3072, 512, 0, stream>>>(lq, Kbuf, Vt, lout);
  // overwrite selected rows: out[qrows] = local_out @ proj_w^T + b
  gemm_bt<<<dim3(6, 29), 256, 0, stream>>>(lout, pwb, nullptr, nullptr,
                                           (float*)d_out, nullptr, qrows, biasf, 1);
}